// Round 5
// baseline (258.091 us; speedup 1.0000x reference)
//
#include <hip/hip_runtime.h>
#include <stdint.h>

// Problem constants (fixed by the reference)
#define BB 4
#define T 128           // T1 == T2
#define D 300
#define D4 75           // D/4 float4 chunks
#define NROW 512        // BB*T

// ---------------- Kernel A: projections q = x@WQ.T+bQ, k/v = x@WK.T+bK ----
__global__ __launch_bounds__(320) void proj_kernel(
    const float* __restrict__ query, const float* __restrict__ key,
    const float* __restrict__ value,
    const float* __restrict__ WQ, const float* __restrict__ bQ,
    const float* __restrict__ WK, const float* __restrict__ bK,
    float* __restrict__ qkv /* [3][512][300] */)
{
    const int src  = blockIdx.x >> 6;    // 0=q,1=k,2=v
    const int rblk = blockIdx.x & 63;
    const int r0   = rblk * 8;
    const float* in   = (src == 0) ? query : (src == 1 ? key : value);
    const float* W    = (src == 0) ? WQ : WK;
    const float* bias = (src == 0) ? bQ : bK;
    float* out = qkv + src * (NROW * D);

    __shared__ __align__(16) float lds_in[8 * D];   // 9.6 KB
    for (int idx = threadIdx.x; idx < 8 * D; idx += 320)
        lds_in[idx] = in[r0 * D + idx];
    __syncthreads();

    const int t = threadIdx.x;
    if (t < D) {
        float acc[8];
        const float bv = bias[t];
        #pragma unroll
        for (int r = 0; r < 8; ++r) acc[r] = bv;
        const float4* W4 = (const float4*)(W + t * D);
        for (int e4 = 0; e4 < D4; ++e4) {
            const float4 w = W4[e4];
            #pragma unroll
            for (int r = 0; r < 8; ++r) {
                const float4 x = *(const float4*)(&lds_in[r * D + e4 * 4]);
                acc[r] += w.x * x.x + w.y * x.y + w.z * x.z + w.w * x.w;
            }
        }
        #pragma unroll
        for (int r = 0; r < 8; ++r)
            out[(r0 + r) * D + t] = acc[r];
    }
}

// ---------------- Kernel B: streaming scores, microbenchmark-style --------
// R5: no LDS, no barriers. Each wave owns one (b,i) row-segment of 16 j's.
// Inner loop: 4 pairs x 6 float4 loads issued back-to-back (~24 independent
// loads, ~20 KB in flight per wave), then FMAs, then ONE batched shuffle
// reduce per 4 pairs (off the load critical path).
// grid: 1024 blocks x 256 threads = 4096 waves; 512 rows x 8 waves/row.
__global__ __launch_bounds__(256, 4) void score_kernel(
    const float* __restrict__ hL, const float* __restrict__ hR,
    const float* __restrict__ qkv, float* __restrict__ S)
{
    const int gtid = blockIdx.x * 256 + threadIdx.x;
    const int wv   = gtid >> 6;        // 0..4095
    const int lane = gtid & 63;
    const int row  = wv >> 3;          // b*T + i, 0..511
    const int seg  = wv & 7;
    const int b    = row >> 7;
    const int i    = row & 127;
    const int j0   = seg * 16;

    const float4* hL4 = (const float4*)hL;
    const float4* hR4 = (const float4*)hR;
    const float4* q4  = (const float4*)qkv + (size_t)row * D4;
    const float4* k4b = (const float4*)qkv + (size_t)NROW * D4 + (size_t)b * T * D4;

    const bool tail = lane < (D4 - 64);   // lanes 0..10 handle d4 64..74
    const float4 zz = make_float4(0.f, 0.f, 0.f, 0.f);
    const float4 qa = q4[lane];
    const float4 qb = tail ? q4[64 + lane] : zz;

    #pragma unroll
    for (int m = 0; m < 4; ++m) {
        const int j = j0 + m * 4;
        float4 lA[4], lB[4], rA[4], rB[4], kA[4], kB[4];
        #pragma unroll
        for (int u = 0; u < 4; ++u) {
            const size_t pL = ((size_t)row * T + (j + u)) * D4;
            const size_t pR = ((size_t)(b * T + j + u) * T + i) * D4;
            const size_t pK = (size_t)(j + u) * D4;
            lA[u] = hL4[pL + lane];
            rA[u] = hR4[pR + lane];
            kA[u] = k4b[pK + lane];
            lB[u] = tail ? hL4[pL + 64 + lane] : zz;
            rB[u] = tail ? hR4[pR + 64 + lane] : zz;
            kB[u] = tail ? k4b[pK + 64 + lane] : zz;
        }
        float4 s;
        float* sp = &s.x;
        #pragma unroll
        for (int u = 0; u < 4; ++u) {
            float v = (qa.x + lA[u].x) * (kA[u].x + rA[u].x)
                    + (qa.y + lA[u].y) * (kA[u].y + rA[u].y)
                    + (qa.z + lA[u].z) * (kA[u].z + rA[u].z)
                    + (qa.w + lA[u].w) * (kA[u].w + rA[u].w);
            // tail part: qb/lB/kB/rB are all zero when !tail -> contributes 0
            v += (qb.x + lB[u].x) * (kB[u].x + rB[u].x)
               + (qb.y + lB[u].y) * (kB[u].y + rB[u].y)
               + (qb.z + lB[u].z) * (kB[u].z + rB[u].z)
               + (qb.w + lB[u].w) * (kB[u].w + rB[u].w);
            sp[u] = v;
        }
        #pragma unroll
        for (int off = 32; off > 0; off >>= 1) {
            s.x += __shfl_xor(s.x, off, 64);
            s.y += __shfl_xor(s.y, off, 64);
            s.z += __shfl_xor(s.z, off, 64);
            s.w += __shfl_xor(s.w, off, 64);
        }
        if (lane == 0)
            *(float4*)&S[(size_t)row * T + j] = s;
    }
}

// ---------------- Kernel C: double softmax + weighted sum ----------------
// grid: 512 blocks (one per (b,i)), 320 threads.
__global__ __launch_bounds__(320) void out_kernel(
    const float* __restrict__ S, const float* __restrict__ qkv,
    const float* __restrict__ hR, float* __restrict__ outp)
{
    const int b = blockIdx.x >> 7;
    const int i = blockIdx.x & 127;
    __shared__ float sc[T];
    const int tid = threadIdx.x;

    if (tid < 64) {
        const float* Srow = S + (size_t)(b * T + i) * T;
        float s0 = Srow[tid], s1 = Srow[tid + 64];
        float m = fmaxf(s0, s1);
        #pragma unroll
        for (int off = 32; off > 0; off >>= 1) m = fmaxf(m, __shfl_xor(m, off, 64));
        float e0 = __expf(s0 - m), e1 = __expf(s1 - m);
        float sum = e0 + e1;
        #pragma unroll
        for (int off = 32; off > 0; off >>= 1) sum += __shfl_xor(sum, off, 64);
        const float inv = 1.0f / sum;
        float t0 = 1000.0f * (e0 * inv), t1 = 1000.0f * (e1 * inv);
        float m2 = fmaxf(t0, t1);
        #pragma unroll
        for (int off = 32; off > 0; off >>= 1) m2 = fmaxf(m2, __shfl_xor(m2, off, 64));
        float f0 = __expf(t0 - m2), f1 = __expf(t1 - m2);
        float sum2 = f0 + f1;
        #pragma unroll
        for (int off = 32; off > 0; off >>= 1) sum2 += __shfl_xor(sum2, off, 64);
        const float inv2 = 1.0f / sum2;
        sc[tid]      = fminf(fmaxf(f0 * inv2, 0.f), 1.f);
        sc[tid + 64] = fminf(fmaxf(f1 * inv2, 0.f), 1.f);
    }
    __syncthreads();

    if (tid < D) {
        float acc = 0.f;
        const float* vb = qkv + 2 * NROW * D + b * T * D;
        for (int j = 0; j < T; ++j) {
            const float aj = sc[j];        // uniform across block -> no divergence
            if (aj >= 1e-12f)              // sharpened attn ~one-hot; error < 1e-9
                acc += aj * (vb[j * D + tid] + hR[((size_t)(b * T + j) * T + i) * D + tid]);
        }
        outp[(size_t)(b * T + i) * D + tid] = acc;
    }
}

extern "C" void kernel_launch(void* const* d_in, const int* in_sizes, int n_in,
                              void* d_out, int out_size, void* d_ws, size_t ws_size,
                              hipStream_t stream) {
    const float* query = (const float*)d_in[0];
    const float* key   = (const float*)d_in[1];
    const float* value = (const float*)d_in[2];
    const float* hL    = (const float*)d_in[3];
    const float* hR    = (const float*)d_in[4];
    const float* WQ    = (const float*)d_in[5];
    const float* bQ    = (const float*)d_in[6];
    const float* WK    = (const float*)d_in[7];
    const float* bK    = (const float*)d_in[8];
    float* out = (float*)d_out;
    float* qkv = (float*)d_ws;                       // 3*512*300 floats = 1.84 MB
    float* S   = qkv + 3 * NROW * D;                 // 512*128 floats = 256 KB

    proj_kernel<<<dim3(192), dim3(320), 0, stream>>>(query, key, value, WQ, bQ, WK, bK, qkv);
    score_kernel<<<dim3(1024), dim3(256), 0, stream>>>(hL, hR, qkv, S);
    out_kernel<<<dim3(512), dim3(320), 0, stream>>>(S, qkv, hR, out);
}

// Round 6
// 235.020 us; speedup vs baseline: 1.0982x; 1.0982x over previous
//
#include <hip/hip_runtime.h>
#include <stdint.h>

// Problem constants (fixed by the reference)
#define BB 4
#define T 128           // T1 == T2
#define D 300
#define D4 75           // D/4 float4 chunks
#define NROW 512        // BB*T

// ---------------- Kernel A: projections q = x@WQ.T+bQ, k/v = x@WK.T+bK ----
__global__ __launch_bounds__(320) void proj_kernel(
    const float* __restrict__ query, const float* __restrict__ key,
    const float* __restrict__ value,
    const float* __restrict__ WQ, const float* __restrict__ bQ,
    const float* __restrict__ WK, const float* __restrict__ bK,
    float* __restrict__ qkv /* [3][512][300] */)
{
    const int src  = blockIdx.x >> 6;    // 0=q,1=k,2=v
    const int rblk = blockIdx.x & 63;
    const int r0   = rblk * 8;
    const float* in   = (src == 0) ? query : (src == 1 ? key : value);
    const float* W    = (src == 0) ? WQ : WK;
    const float* bias = (src == 0) ? bQ : bK;
    float* out = qkv + src * (NROW * D);

    __shared__ __align__(16) float lds_in[8 * D];   // 9.6 KB
    for (int idx = threadIdx.x; idx < 8 * D; idx += 320)
        lds_in[idx] = in[r0 * D + idx];
    __syncthreads();

    const int t = threadIdx.x;
    if (t < D) {
        float acc[8];
        const float bv = bias[t];
        #pragma unroll
        for (int r = 0; r < 8; ++r) acc[r] = bv;
        const float4* W4 = (const float4*)(W + t * D);
        for (int e4 = 0; e4 < D4; ++e4) {
            const float4 w = W4[e4];
            #pragma unroll
            for (int r = 0; r < 8; ++r) {
                const float4 x = *(const float4*)(&lds_in[r * D + e4 * 4]);
                acc[r] += w.x * x.x + w.y * x.y + w.z * x.z + w.w * x.w;
            }
        }
        #pragma unroll
        for (int r = 0; r < 8; ++r)
            out[(r0 + r) * D + t] = acc[r];
    }
}

// Per-batch load bundle: 2 (i,j) pairs x 6 float4 = 12 float4 (48 VGPRs).
struct Batch {
    float4 lA[2], lB[2], rA[2], rB[2], kA[2], kB[2];
};

// ---------------- Kernel B: streaming scores, spill-free deep-MLP ---------
// R6: R5's barrier-free streaming structure with the spills removed.
// Each wave owns 8 j's of one (b,i) row: 4 batches of 2 pairs, software-
// pipelined one batch ahead (~24 independent loads in flight, ~96 VGPR of
// data). 512 rows x 16 segs = 8192 waves. No LDS, no barriers.
__global__ __launch_bounds__(256, 2) void score_kernel(
    const float* __restrict__ hL, const float* __restrict__ hR,
    const float* __restrict__ qkv, float* __restrict__ S)
{
    const int gtid = blockIdx.x * 256 + threadIdx.x;
    const int wv   = gtid >> 6;        // 0..8191
    const int lane = gtid & 63;
    const int row  = wv >> 4;          // b*T + i, 0..511
    const int seg  = wv & 15;
    const int b    = row >> 7;
    const int i    = row & 127;
    const int j0   = seg * 8;

    const float4* hL4 = (const float4*)hL;
    const float4* hR4 = (const float4*)hR;
    const float4* q4  = (const float4*)qkv + (size_t)row * D4;
    const float4* k4b = (const float4*)qkv + (size_t)NROW * D4 + (size_t)b * T * D4;

    const bool tail = lane < (D4 - 64);   // lanes 0..10 cover d4 = 64..74
    const float4 zz = make_float4(0.f, 0.f, 0.f, 0.f);
    const float4 qa = q4[lane];
    const float4 qb = tail ? q4[64 + lane] : zz;

    #define LOAD_BATCH(dst, m)                                              \
        {                                                                   \
            _Pragma("unroll")                                               \
            for (int u = 0; u < 2; ++u) {                                   \
                const int j = j0 + (m) * 2 + u;                             \
                const size_t pL = ((size_t)row * T + j) * D4;               \
                const size_t pR = ((size_t)(b * T + j) * T + i) * D4;       \
                const size_t pK = (size_t)j * D4;                           \
                dst.lA[u] = hL4[pL + lane];                                 \
                dst.rA[u] = hR4[pR + lane];                                 \
                dst.kA[u] = k4b[pK + lane];                                 \
                dst.lB[u] = tail ? hL4[pL + 64 + lane] : zz;                \
                dst.rB[u] = tail ? hR4[pR + 64 + lane] : zz;                \
                dst.kB[u] = tail ? k4b[pK + 64 + lane] : zz;                \
            }                                                               \
        }

    Batch cur, nxt;
    LOAD_BATCH(cur, 0);

    #pragma unroll
    for (int m = 0; m < 4; ++m) {
        if (m < 3) LOAD_BATCH(nxt, m + 1);

        float s0, s1;
        #pragma unroll
        for (int u = 0; u < 2; ++u) {
            float v = (qa.x + cur.lA[u].x) * (cur.kA[u].x + cur.rA[u].x)
                    + (qa.y + cur.lA[u].y) * (cur.kA[u].y + cur.rA[u].y)
                    + (qa.z + cur.lA[u].z) * (cur.kA[u].z + cur.rA[u].z)
                    + (qa.w + cur.lA[u].w) * (cur.kA[u].w + cur.rA[u].w);
            v += (qb.x + cur.lB[u].x) * (cur.kB[u].x + cur.rB[u].x)
               + (qb.y + cur.lB[u].y) * (cur.kB[u].y + cur.rB[u].y)
               + (qb.z + cur.lB[u].z) * (cur.kB[u].z + cur.rB[u].z)
               + (qb.w + cur.lB[u].w) * (cur.kB[u].w + cur.rB[u].w);
            if (u == 0) s0 = v; else s1 = v;
        }
        #pragma unroll
        for (int off = 32; off > 0; off >>= 1) {
            s0 += __shfl_xor(s0, off, 64);
            s1 += __shfl_xor(s1, off, 64);
        }
        if (lane == 0) {
            S[(size_t)row * T + j0 + m * 2]     = s0;
            S[(size_t)row * T + j0 + m * 2 + 1] = s1;
        }
        cur = nxt;
    }
    #undef LOAD_BATCH
}

// ---------------- Kernel C: double softmax + weighted sum ----------------
// grid: 512 blocks (one per (b,i)), 320 threads.
__global__ __launch_bounds__(320) void out_kernel(
    const float* __restrict__ S, const float* __restrict__ qkv,
    const float* __restrict__ hR, float* __restrict__ outp)
{
    const int b = blockIdx.x >> 7;
    const int i = blockIdx.x & 127;
    __shared__ float sc[T];
    const int tid = threadIdx.x;

    if (tid < 64) {
        const float* Srow = S + (size_t)(b * T + i) * T;
        float s0 = Srow[tid], s1 = Srow[tid + 64];
        float m = fmaxf(s0, s1);
        #pragma unroll
        for (int off = 32; off > 0; off >>= 1) m = fmaxf(m, __shfl_xor(m, off, 64));
        float e0 = __expf(s0 - m), e1 = __expf(s1 - m);
        float sum = e0 + e1;
        #pragma unroll
        for (int off = 32; off > 0; off >>= 1) sum += __shfl_xor(sum, off, 64);
        const float inv = 1.0f / sum;
        float t0 = 1000.0f * (e0 * inv), t1 = 1000.0f * (e1 * inv);
        float m2 = fmaxf(t0, t1);
        #pragma unroll
        for (int off = 32; off > 0; off >>= 1) m2 = fmaxf(m2, __shfl_xor(m2, off, 64));
        float f0 = __expf(t0 - m2), f1 = __expf(t1 - m2);
        float sum2 = f0 + f1;
        #pragma unroll
        for (int off = 32; off > 0; off >>= 1) sum2 += __shfl_xor(sum2, off, 64);
        const float inv2 = 1.0f / sum2;
        sc[tid]      = fminf(fmaxf(f0 * inv2, 0.f), 1.f);
        sc[tid + 64] = fminf(fmaxf(f1 * inv2, 0.f), 1.f);
    }
    __syncthreads();

    if (tid < D) {
        float acc = 0.f;
        const float* vb = qkv + 2 * NROW * D + b * T * D;
        for (int j = 0; j < T; ++j) {
            const float aj = sc[j];        // uniform across block -> no divergence
            if (aj >= 1e-12f)              // sharpened attn ~one-hot; error < 1e-9
                acc += aj * (vb[j * D + tid] + hR[((size_t)(b * T + j) * T + i) * D + tid]);
        }
        outp[(size_t)(b * T + i) * D + tid] = acc;
    }
}

extern "C" void kernel_launch(void* const* d_in, const int* in_sizes, int n_in,
                              void* d_out, int out_size, void* d_ws, size_t ws_size,
                              hipStream_t stream) {
    const float* query = (const float*)d_in[0];
    const float* key   = (const float*)d_in[1];
    const float* value = (const float*)d_in[2];
    const float* hL    = (const float*)d_in[3];
    const float* hR    = (const float*)d_in[4];
    const float* WQ    = (const float*)d_in[5];
    const float* bQ    = (const float*)d_in[6];
    const float* WK    = (const float*)d_in[7];
    const float* bK    = (const float*)d_in[8];
    float* out = (float*)d_out;
    float* qkv = (float*)d_ws;                       // 3*512*300 floats = 1.84 MB
    float* S   = qkv + 3 * NROW * D;                 // 512*128 floats = 256 KB

    proj_kernel<<<dim3(192), dim3(320), 0, stream>>>(query, key, value, WQ, bQ, WK, bK, qkv);
    score_kernel<<<dim3(2048), dim3(256), 0, stream>>>(hL, hR, qkv, S);
    out_kernel<<<dim3(512), dim3(320), 0, stream>>>(S, qkv, hR, out);
}

// Round 7
// 226.814 us; speedup vs baseline: 1.1379x; 1.0362x over previous
//
#include <hip/hip_runtime.h>

// Problem constants (fixed by the reference)
#define BB 4
#define T 128           // T1 == T2
#define D 300
#define D4 75           // D/4 float4 chunks
#define NROW 512        // BB*T

// Session findings (R1-R6):
// - The hL/hR stream (157 MB, read-once, no XCD-L2 reuse possible) runs at
//   ~2.45 TB/s effective regardless of structure: occupancy 26->75% (R2),
//   4.8KB-contiguous LDS tiles (R3), 10-deep async global_load_lds (R4),
//   register pipelines (R5/R6) all land 62-68 us. Fully-L3-resident case
//   (R1 ord93) is the same speed -> shared bottleneck is the XCD<->fabric
//   read path (~315 GB/s/XCD). This phase is at its floor.
// - Each extra kernel dispatch costs ~11 us end-to-end (3-kernel rounds
//   total ~173 us over score time; 2-kernel rounds ~161 us). So the best
//   config is 2 kernels: proj + fully fused attn (R2's 66 us kernel).

// ---------------- Kernel A: projections q = x@WQ.T+bQ, k/v = x@WK.T+bK ----
__global__ __launch_bounds__(320) void proj_kernel(
    const float* __restrict__ query, const float* __restrict__ key,
    const float* __restrict__ value,
    const float* __restrict__ WQ, const float* __restrict__ bQ,
    const float* __restrict__ WK, const float* __restrict__ bK,
    float* __restrict__ qkv /* [3][512][300] */)
{
    const int src  = blockIdx.x >> 6;    // 0=q,1=k,2=v
    const int rblk = blockIdx.x & 63;
    const int r0   = rblk * 8;
    const float* in   = (src == 0) ? query : (src == 1 ? key : value);
    const float* W    = (src == 0) ? WQ : WK;
    const float* bias = (src == 0) ? bQ : bK;
    float* out = qkv + src * (NROW * D);

    __shared__ __align__(16) float lds_in[8 * D];   // 9.6 KB
    for (int idx = threadIdx.x; idx < 8 * D; idx += 320)
        lds_in[idx] = in[r0 * D + idx];
    __syncthreads();

    const int t = threadIdx.x;
    if (t < D) {
        float acc[8];
        const float bv = bias[t];
        #pragma unroll
        for (int r = 0; r < 8; ++r) acc[r] = bv;
        const float4* W4 = (const float4*)(W + t * D);
        for (int e4 = 0; e4 < D4; ++e4) {
            const float4 w = W4[e4];
            #pragma unroll
            for (int r = 0; r < 8; ++r) {
                const float4 x = *(const float4*)(&lds_in[r * D + e4 * 4]);
                acc[r] += w.x * x.x + w.y * x.y + w.z * x.z + w.w * x.w;
            }
        }
        #pragma unroll
        for (int r = 0; r < 8; ++r)
            out[(r0 + r) * D + t] = acc[r];
    }
}

// ---------------- Kernel B: fused scores -> double softmax -> output ------
// grid: 512 blocks (one per (b,i)), 1024 threads (16 waves).
// Streaming phase runs at the ~2.45 TB/s fabric plateau (measured floor).
__global__ __launch_bounds__(1024) void attn_kernel(
    const float* __restrict__ hL, const float* __restrict__ hR,
    const float* __restrict__ qkv, float* __restrict__ outp)
{
    const int b = blockIdx.x >> 7;
    const int i = blockIdx.x & 127;

    const float* qp    = qkv + (b * T + i) * D;
    const float* kbase = qkv + NROW * D + b * T * D;
    const float* vbase = qkv + 2 * NROW * D + b * T * D;

    __shared__ __align__(16) float q_lds[D];
    __shared__ float sc[T];
    __shared__ __align__(16) float red[12][D];   // 14.4 KB

    for (int idx = threadIdx.x; idx < D; idx += 1024) q_lds[idx] = qp[idx];
    __syncthreads();

    const int wave = threadIdx.x >> 6;   // 0..15
    const int lane = threadIdx.x & 63;

    // ---- pass 1: scores[j] = sum_d (q_d + hL[i,j,d]) * (k_jd + hR[j,i,d]) ----
    const float4* hL4 = (const float4*)(hL + (size_t)(b * T + i) * T * D);
    for (int j = wave; j < T; j += 16) {       // 8 iterations per wave
        const float4* hRrow = (const float4*)(hR + ((size_t)(b * T + j) * T + i) * D);
        const float4* krow  = (const float4*)(kbase + j * D);
        float4 a = {0.f, 0.f, 0.f, 0.f};
        #pragma unroll
        for (int it = 0; it < 2; ++it) {
            const int d4 = lane + it * 64;
            if (d4 < D4) {
                const float4 l  = hL4[j * D4 + d4];
                const float4 r  = hRrow[d4];
                const float4 kk = krow[d4];
                const float4 qq = *(const float4*)(&q_lds[d4 * 4]);
                a.x += (qq.x + l.x) * (kk.x + r.x);
                a.y += (qq.y + l.y) * (kk.y + r.y);
                a.z += (qq.z + l.z) * (kk.z + r.z);
                a.w += (qq.w + l.w) * (kk.w + r.w);
            }
        }
        float s = a.x + a.y + a.z + a.w;
        #pragma unroll
        for (int off = 32; off > 0; off >>= 1)
            s += __shfl_down(s, off, 64);
        if (lane == 0) sc[j] = s;
    }
    __syncthreads();

    // ---- softmax + sharpening (wave 0 only; 2 scores per lane) ----
    if (wave == 0) {
        float s0 = sc[lane], s1 = sc[lane + 64];
        float m = fmaxf(s0, s1);
        #pragma unroll
        for (int off = 32; off > 0; off >>= 1) m = fmaxf(m, __shfl_xor(m, off, 64));
        float e0 = __expf(s0 - m), e1 = __expf(s1 - m);
        float sum = e0 + e1;
        #pragma unroll
        for (int off = 32; off > 0; off >>= 1) sum += __shfl_xor(sum, off, 64);
        const float inv = 1.0f / sum;
        // sharpen: softmax(1000 * p), clamp to [0,1]
        float t0 = 1000.0f * (e0 * inv), t1 = 1000.0f * (e1 * inv);
        float m2 = fmaxf(t0, t1);
        #pragma unroll
        for (int off = 32; off > 0; off >>= 1) m2 = fmaxf(m2, __shfl_xor(m2, off, 64));
        float f0 = __expf(t0 - m2), f1 = __expf(t1 - m2);
        float sum2 = f0 + f1;
        #pragma unroll
        for (int off = 32; off > 0; off >>= 1) sum2 += __shfl_xor(sum2, off, 64);
        const float inv2 = 1.0f / sum2;
        sc[lane]      = fminf(fmaxf(f0 * inv2, 0.f), 1.f);
        sc[lane + 64] = fminf(fmaxf(f1 * inv2, 0.f), 1.f);
    }
    __syncthreads();

    // ---- pass 2: out[d] = sum_j attn_j * (v[j,d] + hR[j,i,d]) ----
    // Sharpened attn is ~one-hot: the 1e-12 skip avoids nearly all loads
    // (surviving hR rows are L3-hot from pass 1).
    const int tid = threadIdx.x;
    if (tid < 12 * D4) {
        const int grp = tid / D4;    // 0..11: j-split
        const int d4  = tid % D4;
        float4 acc = {0.f, 0.f, 0.f, 0.f};
        for (int j = grp; j < T; j += 12) {
            const float aj = sc[j];
            if (aj >= 1e-12f) {      // skip error bound < 1e-9 << 0.104 threshold
                const float4 v4 = *(const float4*)(vbase + j * D + d4 * 4);
                const float4 r4 = *(const float4*)(hR + ((size_t)(b * T + j) * T + i) * D + d4 * 4);
                acc.x += aj * (v4.x + r4.x);
                acc.y += aj * (v4.y + r4.y);
                acc.z += aj * (v4.z + r4.z);
                acc.w += aj * (v4.w + r4.w);
            }
        }
        *(float4*)(&red[grp][d4 * 4]) = acc;
    }
    __syncthreads();
    if (tid < D4) {
        float4 o = {0.f, 0.f, 0.f, 0.f};
        #pragma unroll
        for (int g = 0; g < 12; ++g) {
            const float4 p = *(const float4*)(&red[g][tid * 4]);
            o.x += p.x; o.y += p.y; o.z += p.z; o.w += p.w;
        }
        *(float4*)(outp + (size_t)(b * T + i) * D + tid * 4) = o;
    }
}

extern "C" void kernel_launch(void* const* d_in, const int* in_sizes, int n_in,
                              void* d_out, int out_size, void* d_ws, size_t ws_size,
                              hipStream_t stream) {
    const float* query = (const float*)d_in[0];
    const float* key   = (const float*)d_in[1];
    const float* value = (const float*)d_in[2];
    const float* hL    = (const float*)d_in[3];
    const float* hR    = (const float*)d_in[4];
    const float* WQ    = (const float*)d_in[5];
    const float* bQ    = (const float*)d_in[6];
    const float* WK    = (const float*)d_in[7];
    const float* bK    = (const float*)d_in[8];
    float* out = (float*)d_out;
    float* qkv = (float*)d_ws;   // 3*512*300*4 = 1.84 MB

    proj_kernel<<<dim3(192), dim3(320), 0, stream>>>(query, key, value, WQ, bQ, WK, bK, qkv);
    attn_kernel<<<dim3(512), dim3(1024), 0, stream>>>(hL, hR, qkv, out);
}